// Round 7
// baseline (340.037 us; speedup 1.0000x reference)
//
#include <hip/hip_runtime.h>
#include <hip/hip_bf16.h>
#include <math.h>

// Problem constants
#define NNODES 200000
#define NGRAPH 100
#define HD     128      // H == NF == 128
#define NCH    3        // virtual channels
#define BN     64       // nodes per block
#define EROWS  (BN*NCH) // 192 (node,channel) pairs per block
#define ESTR   136      // plane row stride in shorts (272B -> bank advance 4)
#define PL     (BN*ESTR)
//
// r7 RESTRUCTURE: 2-plane + reg-staged third channel.
// LDS/wave was the occupancy cap (3 planes = 52.7KB -> 3 blocks/CU = 12
// waves/CU at any BN). This version keeps r2's proven dataflow (GEMM1 once,
// acc1 held through ALL ep1's — no recompute (r5 disaster), no bf16
// compression of P (precision), no forced launch_bounds (r3/r5 disaster))
// but stages E1 of channel 2 in 16 u32 REGISTERS (the exact ds_write_b128
// payloads) instead of a third LDS plane:
//   ep1: c0->plane0, c1->plane1, c2->e2r[4] (u32x4); acc1 dies here.
//   GEMM2+GEMM3 jointly on planes 0,1 (weight frags amortized 2x, ct-halves
//   -> acc[2][4]=32 live + e2r 16 held).
//   e2r -> plane0 (wave-private rows, same-wave order);
//   GEMM2+GEMM3 c2 full-width on plane0 (weights re-read: +64 L1 loads/wave).
// LDS 52.7 -> 39.1KB -> 4 blocks/CU = 16 waves/CU (+33% latency hiding) IF
// unified VGPR+AGPR stays <=128 (structure sized for ~100-115 peak).
// Kill-switch: FETCH>100MB = spill -> revert; occupancy flat 28% -> revert.
//
// plane cols are K-PERMUTED (pi): col p holds logical h = g(p) =
// ((p&7)<<4)|(p>>3); value for h = ct*16+lrow sits at p = lrow*8+ct ->
// a lane's 8 epilogue values are contiguous 16B -> one ds_write_b128.
// prep repacks w2r/wc1r B-fragments through g() so contractions align.
//
// pack2bf (r2 win; m240 lesson): compiler-visible v_add_u32 x2 + v_perm_b32,
// NOT inline-asm v_cvt_pk (opaque asm defeated the MFMA<->VALU interleave).
//
// Slow path (nseg>1, ~3% of blocks): M-plane aggregation needs cross-wave
// reads -> explicit barriers (block-uniform nseg so all waves participate).

typedef short short8 __attribute__((ext_vector_type(8)));
typedef float f32x4  __attribute__((ext_vector_type(4)));
typedef unsigned int u32x2 __attribute__((ext_vector_type(2)));
typedef unsigned int u32x4 __attribute__((ext_vector_type(4)));

#define MFMA_16x16x32(a,b,c) __builtin_amdgcn_mfma_f32_16x16x32_bf16((a),(b),(c),0,0,0)

__device__ __forceinline__ float bf2f(unsigned short u) {
    return __uint_as_float(((unsigned int)u) << 16);
}
// round-half-up: 2 VALU ops; ties measure-zero for arithmetic-derived floats.
__device__ __forceinline__ unsigned short f2bf(float f) {
    return (unsigned short)((__float_as_uint(f) + 0x8000u) >> 16);
}
// Pack two f32 -> bf16x2 (round-half-up, same as f2bf), compiler-visible:
// 2x v_add_u32 + 1x v_perm_b32.
__device__ __forceinline__ unsigned int pack2bf(float lo, float hi) {
    unsigned int a = __float_as_uint(lo) + 0x8000u;
    unsigned int b = __float_as_uint(hi) + 0x8000u;
    return __builtin_amdgcn_perm(b, a, 0x07060302u);
}
__device__ __forceinline__ short8 as_short8(u32x4 v) {
    union { u32x4 u; short8 s; } x; x.u = v; return x.s;
}
__device__ __forceinline__ float silu_f(float x) {
    return x * __builtin_amdgcn_rcpf(1.0f + __expf(-x));
}

// ---------------------------------------------------------------------------
// prep: blocks [0,192) repack We1[0:128]/We2/Wc1 into bf16 MFMA B-frag order.
//   fragment k-row index kf = ks*32+(l>>4)*8+j; source row:
//     w1r  : kf          (GEMM1 contracts over raw node_feat order)
//     w2r/wc1r: g(kf) = ((kf&7)<<4)|(kf>>3)   (match pi-permuted plane cols)
// blocks [192,492) compute Q[b,c,h] = sum_k vnf[b,k,c]*We1[128+k,h]
// blocks [492,646) zero the accumulators (replaces hipMemsetAsync dispatch)
// ---------------------------------------------------------------------------
__global__ void prep_kernel(const float* __restrict__ We1,
                            const float* __restrict__ We2,
                            const float* __restrict__ Wc1,
                            const float* __restrict__ be1,
                            const float* __restrict__ be2,
                            const float* __restrict__ bc1,
                            const float* __restrict__ Wc2,
                            const float* __restrict__ vnf,
                            unsigned short* __restrict__ w1r,
                            unsigned short* __restrict__ w2r,
                            unsigned short* __restrict__ wc1r,
                            float* __restrict__ Q,
                            float* __restrict__ wlast,
                            float* __restrict__ be1f,
                            float* __restrict__ be2f,
                            float* __restrict__ bc1f,
                            float* __restrict__ wc2f,
                            float* __restrict__ zacc) {
    int bid = blockIdx.x;
    if (bid < 192) {
        int t = bid * 256 + threadIdx.x;   // < 49152 = 3*16384
        int m  = t / 16384;
        int e  = t % 16384;
        int j  = e & 7;
        int l  = (e >> 3) & 63;
        int ks = (e >> 9) & 3;
        int ct = e >> 11;
        int kf  = ks * 32 + (l >> 4) * 8 + j;
        int col = ct * 16 + (l & 15);
        int srck = (m == 0) ? kf : (((kf & 7) << 4) | (kf >> 3));
        const float*    src = (m == 0) ? We1 : ((m == 1) ? We2 : Wc1);
        unsigned short* dst = (m == 0) ? w1r : ((m == 1) ? w2r : wc1r);
        dst[e] = f2bf(src[srck * 128 + col]);
        if (t < 128) {
            wlast[t] = We1[256 * 128 + t];
            be1f[t]  = be1[t];
            be2f[t]  = be2[t];
            bc1f[t]  = bc1[t];
            wc2f[t]  = Wc2[t];
        }
    } else if (bid < 492) {
        int bc = bid - 192;                // 0..299
        int b = bc / NCH, c = bc % NCH;
        int t = threadIdx.x;
        __shared__ float v[128];
        if (t < 128) v[t] = vnf[(b * 128 + t) * 3 + c];
        __syncthreads();
        if (t < 128) {
            // 4 independent partials: breaks the 128-deep dependent FMA chain
            float s0 = 0.f, s1 = 0.f, s2 = 0.f, s3 = 0.f;
            for (int k = 0; k < 128; k += 4) {
                s0 += v[k + 0] * We1[(128 + k + 0) * 128 + t];
                s1 += v[k + 1] * We1[(128 + k + 1) * 128 + t];
                s2 += v[k + 2] * We1[(128 + k + 2) * 128 + t];
                s3 += v[k + 3] * We1[(128 + k + 3) * 128 + t];
            }
            Q[(b * 3 + c) * 128 + t] = (s0 + s1) + (s2 + s3);
        }
    } else {
        int idx = (bid - 492) * 256 + threadIdx.x;
        if (idx < 39400) zacc[idx] = 0.0f;   // aggsum+transsum+cnt = 157600 B
    }
}

// ---------------------------------------------------------------------------
// Main fused kernel: 64 nodes/block, 256 threads (4 waves), 3125 blocks.
// ---------------------------------------------------------------------------
__global__ __launch_bounds__(256, 2) void egcl_main(
    const float* __restrict__ node_feat,   // [N,128]
    const float* __restrict__ coord,       // [N,3]
    const float* __restrict__ vcoord,      // [B,3,C]
    const int*   __restrict__ batch,       // [N] sorted
    const unsigned short* __restrict__ w1r,
    const unsigned short* __restrict__ w2r,
    const unsigned short* __restrict__ wc1r,
    const float* __restrict__ Q,           // [B,C,H]
    const float* __restrict__ wlast,
    const float* __restrict__ be1f,
    const float* __restrict__ be2f,
    const float* __restrict__ bc1f,
    const float* __restrict__ wc2f,
    float* __restrict__ aggsum,            // [B,C,H]
    float* __restrict__ transsum,          // [B,3,C]
    float* __restrict__ cnt)               // [B]
{
    __shared__ __align__(16) unsigned short planes[2][PL];   // 34816 B
    __shared__ __align__(16) float pad_buf[EROWS * 4];       // dx,dy,dz,rad
    __shared__ float s_vals[EROWS];                          // per-(c,node) s
    __shared__ unsigned short sbatch[BN];
    __shared__ unsigned short sseg_start[BN + 1];
    __shared__ unsigned short sseg_b[BN];
    __shared__ int snseg;

    const int tid   = threadIdx.x;
    const int wave  = tid >> 6;
    const int lane  = tid & 63;
    const int lrow  = lane & 15;           // MFMA row (A) / col (D) index
    const int lkb   = (lane >> 4) * 8;     // k-offset base within 32-wide K step
    const int rq    = (lane >> 4) * 4;     // D row-group base
    const int node0 = blockIdx.x * BN;
    const int myrow = wave * 16 + lrow;    // this lane's A-row in a plane

    // ---- Phase 0 ----
    if (tid < BN) {  // wave 0
        int n = node0 + tid;
        int b = batch[n];
        sbatch[tid] = (unsigned short)b;
        int prev = (tid > 0) ? batch[n - 1] : -1;
        unsigned long long mask = __ballot(b != prev);
        int ns = __popcll(mask);
        if (b != prev) {
            int idx = __popcll(mask & ((1ull << tid) - 1ull));
            sseg_start[idx] = (unsigned short)tid;
            sseg_b[idx]     = (unsigned short)b;
        }
        if (tid == 0) { sseg_start[ns] = BN; snseg = ns; }
        float cx = coord[n * 3 + 0];
        float cy = coord[n * 3 + 1];
        float cz = coord[n * 3 + 2];
        for (int c = 0; c < 3; ++c) {
            float dx = vcoord[b * 9 + 0 * 3 + c] - cx;
            float dy = vcoord[b * 9 + 1 * 3 + c] - cy;
            float dz = vcoord[b * 9 + 2 * 3 + c] - cz;
            f32x4 pad;
            pad[0] = dx; pad[1] = dy; pad[2] = dz;
            pad[3] = sqrtf(dx * dx + dy * dy + dz * dz);
            *(f32x4*)&pad_buf[(c * 64 + tid) * 4] = pad;  // 16B aligned
        }
    }
    __syncthreads();
    const int nseg = snseg;   // block-uniform

    // ---- GEMM1: P[64,128] = node_feat_tile @ We1_top ----
    f32x4 acc1[8] = {};
    {
        const float* arow = node_feat + (size_t)(node0 + myrow) * 128;
        for (int ks = 0; ks < 4; ++ks) {
            f32x4 x0 = *(const f32x4*)(arow + ks * 32 + lkb);
            f32x4 x1 = *(const f32x4*)(arow + ks * 32 + lkb + 4);
            u32x4 av;
            av[0] = pack2bf(x0[0], x0[1]);
            av[1] = pack2bf(x0[2], x0[3]);
            av[2] = pack2bf(x1[0], x1[1]);
            av[3] = pack2bf(x1[2], x1[3]);
            short8 af = as_short8(av);
            for (int ct = 0; ct < 8; ++ct) {
                short8 bfg = *(const short8*)(w1r + ((ct * 4 + ks) * 64 + lane) * 8);
                acc1[ct] = MFMA_16x16x32(af, bfg, acc1[ct]);
            }
        }
    }

    const int bagg = (nseg == 1) ? (int)sseg_b[0] * (NCH * HD) : 0;

    // ---- Epilogue 1: all three channels while acc1 is live.
    //      c0 -> plane0, c1 -> plane1, c2 -> e2r (regs). acc1 dies here. ----
    u32x4 e2r[4];
    {
        float wl[8];
        #pragma unroll
        for (int ct = 0; ct < 8; ++ct)
            wl[ct] = wlast[ct * 16 + lrow];
        if (nseg == 1) {
            const float* qb = Q + bagg;
            float qv[3][8];   // bias folded in
            #pragma unroll
            for (int c = 0; c < 3; ++c)
                #pragma unroll
                for (int ct = 0; ct < 8; ++ct)
                    qv[c][ct] = qb[c * 128 + ct * 16 + lrow] + be1f[ct * 16 + lrow];
            #pragma unroll
            for (int r = 0; r < 4; ++r) {
                int nl = wave * 16 + rq + r;
                #pragma unroll
                for (int c = 0; c < 3; ++c) {
                    float rad = pad_buf[(c * 64 + nl) * 4 + 3];
                    float v[8];
                    #pragma unroll
                    for (int ct = 0; ct < 8; ++ct)
                        v[ct] = silu_f(acc1[ct][r] + qv[c][ct] + rad * wl[ct]);
                    u32x4 av;
                    av[0] = pack2bf(v[0], v[1]);
                    av[1] = pack2bf(v[2], v[3]);
                    av[2] = pack2bf(v[4], v[5]);
                    av[3] = pack2bf(v[6], v[7]);
                    if (c < 2) *(u32x4*)&planes[c][nl * ESTR + lrow * 8] = av;
                    else       e2r[r] = av;
                }
            }
        } else {
            float bb[8];
            #pragma unroll
            for (int ct = 0; ct < 8; ++ct)
                bb[ct] = be1f[ct * 16 + lrow];
            #pragma unroll
            for (int r = 0; r < 4; ++r) {
                int nl = wave * 16 + rq + r;
                int b  = sbatch[nl];
                #pragma unroll
                for (int c = 0; c < 3; ++c) {
                    float rad = pad_buf[(c * 64 + nl) * 4 + 3];
                    const float* qb = Q + (b * 3 + c) * 128;
                    float v[8];
                    #pragma unroll
                    for (int ct = 0; ct < 8; ++ct)
                        v[ct] = silu_f(acc1[ct][r] + bb[ct] + qb[ct * 16 + lrow]
                                       + rad * wl[ct]);
                    u32x4 av;
                    av[0] = pack2bf(v[0], v[1]);
                    av[1] = pack2bf(v[2], v[3]);
                    av[2] = pack2bf(v[4], v[5]);
                    av[3] = pack2bf(v[6], v[7]);
                    if (c < 2) *(u32x4*)&planes[c][nl * ESTR + lrow * 8] = av;
                    else       e2r[r] = av;
                }
            }
        }
    }
    asm volatile("" ::: "memory");  // ep1 stores precede GEMM2 loads

    // ---- GEMM2 c0+c1 (joint, weights amortized 2x), ct-halves ----
    for (int half = 0; half < 2; ++half) {
        f32x4 acc[2][4] = {};
        for (int ks = 0; ks < 4; ++ks) {
            short8 af0 = *(const short8*)&planes[0][myrow * ESTR + ks * 32 + lkb];
            short8 af1 = *(const short8*)&planes[1][myrow * ESTR + ks * 32 + lkb];
            #pragma unroll
            for (int c4 = 0; c4 < 4; ++c4) {
                int ct = half * 4 + c4;
                short8 bfg = *(const short8*)(w2r + ((ct * 4 + ks) * 64 + lane) * 8);
                acc[0][c4] = MFMA_16x16x32(af0, bfg, acc[0][c4]);
                acc[1][c4] = MFMA_16x16x32(af1, bfg, acc[1][c4]);
            }
        }
        float b0 = be2f[(half * 4 + 0) * 16 + lrow];
        float b1 = be2f[(half * 4 + 1) * 16 + lrow];
        float b2 = be2f[(half * 4 + 2) * 16 + lrow];
        float b3 = be2f[(half * 4 + 3) * 16 + lrow];
        #pragma unroll
        for (int j = 0; j < 2; ++j) {
            float ps0 = 0.f, ps1 = 0.f, ps2 = 0.f, ps3 = 0.f;
            #pragma unroll
            for (int r = 0; r < 4; ++r) {
                int nl = wave * 16 + rq + r;
                float v0 = silu_f(acc[j][0][r] + b0);
                float v1 = silu_f(acc[j][1][r] + b1);
                float v2 = silu_f(acc[j][2][r] + b2);
                float v3 = silu_f(acc[j][3][r] + b3);
                ps0 += v0; ps1 += v1; ps2 += v2; ps3 += v3;
                u32x2 dv;
                dv[0] = pack2bf(v0, v1);
                dv[1] = pack2bf(v2, v3);
                *(u32x2*)&planes[j][nl * ESTR + lrow * 8 + half * 4] = dv;
            }
            if (nseg == 1) {
                ps0 += __shfl_xor(ps0, 16, 64); ps0 += __shfl_xor(ps0, 32, 64);
                ps1 += __shfl_xor(ps1, 16, 64); ps1 += __shfl_xor(ps1, 32, 64);
                ps2 += __shfl_xor(ps2, 16, 64); ps2 += __shfl_xor(ps2, 32, 64);
                ps3 += __shfl_xor(ps3, 16, 64); ps3 += __shfl_xor(ps3, 32, 64);
                if (lane < 16) {
                    atomicAdd(&aggsum[bagg + j * 128 + (half * 4 + 0) * 16 + lane], ps0);
                    atomicAdd(&aggsum[bagg + j * 128 + (half * 4 + 1) * 16 + lane], ps1);
                    atomicAdd(&aggsum[bagg + j * 128 + (half * 4 + 2) * 16 + lane], ps2);
                    atomicAdd(&aggsum[bagg + j * 128 + (half * 4 + 3) * 16 + lane], ps3);
                }
            }
        }
    }
    asm volatile("" ::: "memory");

    // ---- GEMM3 c0+c1 (joint), ct-halves -> s for c0,c1 ----
    {
        float p[2][4] = {};
        for (int half = 0; half < 2; ++half) {
            f32x4 acc[2][4] = {};
            for (int ks = 0; ks < 4; ++ks) {
                short8 af0 = *(const short8*)&planes[0][myrow * ESTR + ks * 32 + lkb];
                short8 af1 = *(const short8*)&planes[1][myrow * ESTR + ks * 32 + lkb];
                #pragma unroll
                for (int c4 = 0; c4 < 4; ++c4) {
                    int ct = half * 4 + c4;
                    short8 bfg = *(const short8*)(wc1r + ((ct * 4 + ks) * 64 + lane) * 8);
                    acc[0][c4] = MFMA_16x16x32(af0, bfg, acc[0][c4]);
                    acc[1][c4] = MFMA_16x16x32(af1, bfg, acc[1][c4]);
                }
            }
            float b0 = bc1f[(half * 4 + 0) * 16 + lrow];
            float b1 = bc1f[(half * 4 + 1) * 16 + lrow];
            float b2 = bc1f[(half * 4 + 2) * 16 + lrow];
            float b3 = bc1f[(half * 4 + 3) * 16 + lrow];
            float w0 = wc2f[(half * 4 + 0) * 16 + lrow];
            float w1 = wc2f[(half * 4 + 1) * 16 + lrow];
            float w2 = wc2f[(half * 4 + 2) * 16 + lrow];
            float w3 = wc2f[(half * 4 + 3) * 16 + lrow];
            #pragma unroll
            for (int j = 0; j < 2; ++j) {
                #pragma unroll
                for (int r = 0; r < 4; ++r) {
                    float s = p[j][r];
                    s += silu_f(acc[j][0][r] + b0) * w0;
                    s += silu_f(acc[j][1][r] + b1) * w1;
                    s += silu_f(acc[j][2][r] + b2) * w2;
                    s += silu_f(acc[j][3][r] + b3) * w3;
                    p[j][r] = s;
                }
            }
        }
        #pragma unroll
        for (int j = 0; j < 2; ++j) {
            float p0 = p[j][0], p1 = p[j][1], p2 = p[j][2], p3 = p[j][3];
            #pragma unroll
            for (int off = 1; off < 16; off <<= 1) {
                p0 += __shfl_xor(p0, off, 64);
                p1 += __shfl_xor(p1, off, 64);
                p2 += __shfl_xor(p2, off, 64);
                p3 += __shfl_xor(p3, off, 64);
            }
            if (lrow == 0) {
                int rbase = j * 64 + wave * 16 + rq;
                s_vals[rbase + 0] = p0;
                s_vals[rbase + 1] = p1;
                s_vals[rbase + 2] = p2;
                s_vals[rbase + 3] = p3;
            }
        }
    }

    // ---- slow-path aggregation for M0,M1 (planes about to be reused) ----
    if (nseg > 1) {
        __syncthreads();   // all waves' M0/M1 written
        for (int sg = 0; sg < nseg; ++sg) {
            int s0 = sseg_start[sg], s1 = sseg_start[sg + 1], b = sseg_b[sg];
            int cj = tid >> 7, pcol = tid & 127;   // 256 threads = 2ch x 128col
            float sum = 0.f;
            for (int ii = s0; ii < s1; ++ii)
                sum += bf2f(planes[cj][ii * ESTR + pcol]);
            int h = ((pcol & 7) << 4) | (pcol >> 3);   // g(p): undo pi
            atomicAdd(&aggsum[(b * 3 + cj) * 128 + h], sum);
        }
        __syncthreads();   // agg reads done before plane0 overwrite
    }
    asm volatile("" ::: "memory");  // GEMM3 reads precede e2r store

    // ---- channel 2: E1 from regs -> plane0, then GEMM2/GEMM3 full-width ----
    #pragma unroll
    for (int r = 0; r < 4; ++r) {
        int nl = wave * 16 + rq + r;
        *(u32x4*)&planes[0][nl * ESTR + lrow * 8] = e2r[r];
    }
    asm volatile("" ::: "memory");
    {
        f32x4 acc2[8] = {};
        for (int ks = 0; ks < 4; ++ks) {
            short8 af = *(const short8*)&planes[0][myrow * ESTR + ks * 32 + lkb];
            #pragma unroll
            for (int ct = 0; ct < 8; ++ct) {
                short8 bfg = *(const short8*)(w2r + ((ct * 4 + ks) * 64 + lane) * 8);
                acc2[ct] = MFMA_16x16x32(af, bfg, acc2[ct]);
            }
        }
        float psum[8];
        #pragma unroll
        for (int ct = 0; ct < 8; ++ct) psum[ct] = 0.0f;
        #pragma unroll
        for (int r = 0; r < 4; ++r) {
            int nl = wave * 16 + rq + r;
            float v[8];
            #pragma unroll
            for (int ct = 0; ct < 8; ++ct) {
                v[ct] = silu_f(acc2[ct][r] + be2f[ct * 16 + lrow]);
                psum[ct] += v[ct];
            }
            u32x4 av;
            av[0] = pack2bf(v[0], v[1]);
            av[1] = pack2bf(v[2], v[3]);
            av[2] = pack2bf(v[4], v[5]);
            av[3] = pack2bf(v[6], v[7]);
            *(u32x4*)&planes[0][nl * ESTR + lrow * 8] = av;
        }
        if (nseg == 1) {
            #pragma unroll
            for (int ct = 0; ct < 8; ++ct) {
                psum[ct] += __shfl_xor(psum[ct], 16, 64);
                psum[ct] += __shfl_xor(psum[ct], 32, 64);
            }
            if (lane < 16) {
                #pragma unroll
                for (int ct = 0; ct < 8; ++ct)
                    atomicAdd(&aggsum[bagg + 2 * 128 + ct * 16 + lane], psum[ct]);
            }
        }
    }
    asm volatile("" ::: "memory");
    {
        f32x4 acc3[8] = {};
        for (int ks = 0; ks < 4; ++ks) {
            short8 af = *(const short8*)&planes[0][myrow * ESTR + ks * 32 + lkb];
            #pragma unroll
            for (int ct = 0; ct < 8; ++ct) {
                short8 bfg = *(const short8*)(wc1r + ((ct * 4 + ks) * 64 + lane) * 8);
                acc3[ct] = MFMA_16x16x32(af, bfg, acc3[ct]);
            }
        }
        float p0 = 0.f, p1 = 0.f, p2 = 0.f, p3 = 0.f;
        #pragma unroll
        for (int ct = 0; ct < 8; ++ct) {
            float bb = bc1f[ct * 16 + lrow];
            float w2 = wc2f[ct * 16 + lrow];
            p0 += silu_f(acc3[ct][0] + bb) * w2;
            p1 += silu_f(acc3[ct][1] + bb) * w2;
            p2 += silu_f(acc3[ct][2] + bb) * w2;
            p3 += silu_f(acc3[ct][3] + bb) * w2;
        }
        #pragma unroll
        for (int off = 1; off < 16; off <<= 1) {
            p0 += __shfl_xor(p0, off, 64);
            p1 += __shfl_xor(p1, off, 64);
            p2 += __shfl_xor(p2, off, 64);
            p3 += __shfl_xor(p3, off, 64);
        }
        if (lrow == 0) {
            int rbase = 2 * 64 + wave * 16 + rq;
            s_vals[rbase + 0] = p0;
            s_vals[rbase + 1] = p1;
            s_vals[rbase + 2] = p2;
            s_vals[rbase + 3] = p3;
        }
    }

    // ---- slow-path aggregation for M2 ----
    if (nseg > 1) {
        __syncthreads();   // all waves' M2 written
        for (int sg = 0; sg < nseg; ++sg) {
            int s0 = sseg_start[sg], s1 = sseg_start[sg + 1], b = sseg_b[sg];
            if (tid < 128) {
                int pcol = tid;
                float sum = 0.f;
                for (int ii = s0; ii < s1; ++ii)
                    sum += bf2f(planes[0][ii * ESTR + pcol]);
                int h = ((pcol & 7) << 4) | (pcol >> 3);
                atomicAdd(&aggsum[(b * 3 + 2) * 128 + h], sum);
            }
        }
    }
    __syncthreads();   // s_vals from all waves visible

    // ---- trans reduction (+cnt) ----
    if (nseg == 1) {
        int b = sseg_b[0];
        if (wave == 0) {   // 64-lane shuffle tree over nodes
            float t[9];
            #pragma unroll
            for (int c = 0; c < 3; ++c) {
                f32x4 pd = *(const f32x4*)&pad_buf[(c * 64 + lane) * 4];
                float sv = s_vals[c * 64 + lane];
                t[0 * 3 + c] = pd[0] * sv;
                t[1 * 3 + c] = pd[1] * sv;
                t[2 * 3 + c] = pd[2] * sv;
            }
            #pragma unroll
            for (int off = 1; off < 64; off <<= 1)
                #pragma unroll
                for (int k = 0; k < 9; ++k)
                    t[k] += __shfl_xor(t[k], off, 64);
            if (lane < 9)
                atomicAdd(&transsum[b * 9 + lane],
                          __shfl(t[lane], 0, 64));  // lane0 holds full sums
            if (lane == 0) atomicAdd(&cnt[b], 64.0f);
        }
    } else {
        if (tid < 9) {
            int d = tid / 3, c = tid % 3;
            for (int sg = 0; sg < nseg; ++sg) {
                int s0 = sseg_start[sg], s1 = sseg_start[sg + 1], b = sseg_b[sg];
                float sum = 0.f;
                for (int ii = s0; ii < s1; ++ii)
                    sum += pad_buf[(c * 64 + ii) * 4 + d] * s_vals[c * 64 + ii];
                atomicAdd(&transsum[b * 9 + d * 3 + c], sum);
            }
        }
        if (tid == 0) {
            for (int sg = 0; sg < nseg; ++sg)
                atomicAdd(&cnt[sseg_b[sg]],
                          (float)(sseg_start[sg + 1] - sseg_start[sg]));
        }
    }
}

// ---------------------------------------------------------------------------
// Finalize: one block per (b,c) row. Means, node model, residuals, outputs.
// ---------------------------------------------------------------------------
__global__ void finalize_kernel(const float* __restrict__ vnf,
                                const float* __restrict__ vcoord,
                                const float* __restrict__ Wn1,
                                const float* __restrict__ bn1,
                                const float* __restrict__ Wn2,
                                const float* __restrict__ bn2,
                                const float* __restrict__ aggsum,
                                const float* __restrict__ transsum,
                                const float* __restrict__ cnt,
                                float* __restrict__ out) {
    int b = blockIdx.x / NCH;
    int c = blockIdx.x % NCH;
    int j = threadIdx.x;   // 0..127
    __shared__ float nin[256];
    __shared__ float h1[128];
    float count = fmaxf(cnt[b], 1.0f);
    nin[j]       = vnf[(b * 128 + j) * 3 + c];
    nin[128 + j] = aggsum[(b * 3 + c) * 128 + j] / count;
    __syncthreads();
    float x0 = bn1[j], x1 = 0.f, x2 = 0.f, x3 = 0.f;
    for (int k = 0; k < 256; k += 4) {
        x0 += nin[k + 0] * Wn1[(k + 0) * 128 + j];
        x1 += nin[k + 1] * Wn1[(k + 1) * 128 + j];
        x2 += nin[k + 2] * Wn1[(k + 2) * 128 + j];
        x3 += nin[k + 3] * Wn1[(k + 3) * 128 + j];
    }
    h1[j] = silu_f((x0 + x1) + (x2 + x3));
    __syncthreads();
    float y0 = bn2[j], y1 = 0.f, y2 = 0.f, y3 = 0.f;
    for (int k = 0; k < 128; k += 4) {
        y0 += h1[k + 0] * Wn2[(k + 0) * 128 + j];
        y1 += h1[k + 1] * Wn2[(k + 1) * 128 + j];
        y2 += h1[k + 2] * Wn2[(k + 2) * 128 + j];
        y3 += h1[k + 3] * Wn2[(k + 3) * 128 + j];
    }
    float y = (y0 + y1) + (y2 + y3);
    out[(b * 128 + j) * 3 + c] = vnf[(b * 128 + j) * 3 + c] + y;
    if (c == 0 && j < 9) {
        out[NGRAPH * 128 * 3 + b * 9 + j] =
            vcoord[b * 9 + j] + transsum[b * 9 + j] / count;
    }
}

// ---------------------------------------------------------------------------
extern "C" void kernel_launch(void* const* d_in, const int* in_sizes, int n_in,
                              void* d_out, int out_size, void* d_ws, size_t ws_size,
                              hipStream_t stream) {
    const float* node_feat = (const float*)d_in[0];
    const float* coord     = (const float*)d_in[1];
    const float* vnf       = (const float*)d_in[2];
    const float* vcoord    = (const float*)d_in[3];
    const int*   batch     = (const int*)d_in[4];
    const float* We1 = (const float*)d_in[5];
    const float* be1 = (const float*)d_in[6];
    const float* We2 = (const float*)d_in[7];
    const float* be2 = (const float*)d_in[8];
    const float* Wc1 = (const float*)d_in[9];
    const float* bc1 = (const float*)d_in[10];
    const float* Wc2 = (const float*)d_in[11];
    const float* Wn1 = (const float*)d_in[12];
    const float* bn1 = (const float*)d_in[13];
    const float* Wn2 = (const float*)d_in[14];
    const float* bn2 = (const float*)d_in[15];

    char* ws = (char*)d_ws;
    float*          aggsum   = (float*)(ws + 0);          // 153600
    float*          transsum = (float*)(ws + 153600);     // 3600
    float*          cntp     = (float*)(ws + 157200);     // 400
    float*          Q        = (float*)(ws + 157600);     // 153600
    unsigned short* w1r      = (unsigned short*)(ws + 311200); // 32768
    unsigned short* w2r      = (unsigned short*)(ws + 343968); // 32768
    unsigned short* wc1r     = (unsigned short*)(ws + 376736); // 32768
    float*          wlast    = (float*)(ws + 409504);
    float*          be1f     = (float*)(ws + 410016);
    float*          be2f     = (float*)(ws + 410528);
    float*          bc1f     = (float*)(ws + 411040);
    float*          wc2f     = (float*)(ws + 411552);

    // accumulator zeroing folded into prep_kernel (blocks [492,646)).
    prep_kernel<<<192 + NGRAPH * NCH + 154, 256, 0, stream>>>(
        We1, We2, Wc1, be1, be2, bc1, Wc2, vnf,
        w1r, w2r, wc1r, Q, wlast, be1f, be2f, bc1f, wc2f,
        (float*)ws);

    egcl_main<<<NNODES / BN, 256, 0, stream>>>(
        node_feat, coord, vcoord, batch, w1r, w2r, wc1r, Q,
        wlast, be1f, be2f, bc1f, wc2f, aggsum, transsum, cntp);

    finalize_kernel<<<NGRAPH * NCH, 128, 0, stream>>>(
        vnf, vcoord, Wn1, bn1, Wn2, bn2, aggsum, transsum, cntp,
        (float*)d_out);
}

// Round 8
// 298.916 us; speedup vs baseline: 1.1376x; 1.1376x over previous
//
#include <hip/hip_runtime.h>
#include <hip/hip_bf16.h>
#include <math.h>

// Problem constants
#define NNODES 200000
#define NGRAPH 100
#define HD     128      // H == NF == 128
#define NCH    3        // virtual channels
#define BN     64       // nodes per block
#define EROWS  (BN*NCH) // 192 e-rows per block
#define ESTR   136      // 128 data + 8 pad cols; row stride 272B (16B aligned)
// Pad cols per row (row' = c*64+nl): [128..129]=fp32 dx, [130..131]=fp32 dy,
// [132..133]=fp32 dz, [134..135]=fp32 radial, OVERWRITTEN by fp32 s after
// epilogue-1 consumes radial (wave-private rows -> no race).
//
// FINAL STRUCTURE (r8 = r6 verbatim; r7 kill-switch fired).
// Occupancy is structurally pinned at ~12 waves/CU by TWO aligned caps:
//   (1) LDS/wave = 3 planes x 16 rows x 272B = 13KB (invariant in BN);
//   (2) regs/wave ~165-170 (acc1 32 + acc 48 + epilogue working set).
// Four restructures tried to break this (r3 1-plane seq + (256,4): spill;
// r4 1-plane seq + (256,2): no spill but serial chain, 283us; r5 recompute-
// GEMM1: spill; r7 2-plane + reg-staged c2: mild spill + occupancy 19.7%,
// 200us). ALL reverted. DO NOT: channel-sequential; launch_bounds min-waves
// >2; holding extra reg state across GEMM2/3. Remaining unexplored door:
// fp8 LDS planes (24 waves/CU) — rejected on precision risk (absmax 0.047
// already near threshold).
//
// e_buf DATA columns are stored K-PERMUTED:
//   column p holds logical h = g(p) = ((p&7)<<4) | (p>>3)   (pi^-1)
//   i.e. a value for h = ct*16 + lrow is stored at p = lrow*8 + ct.
// MFMA D-layout gives each lane 8 values {h = ct*16+lrow}; under pi they are
// CONTIGUOUS 16B -> one ds_write_b128 per group instead of 8 ds_write_b16.
// The h-dim of layer L is only the contraction dim of layer L+1, and prep
// repacks those B matrices through g(), so the contraction stays aligned.
//
// pack2bf (r2 win; m240 lesson): compiler-visible v_add_u32 x2 + v_perm_b32,
// NOT inline-asm v_cvt_pk (opaque asm blocks defeated the scheduler's
// MFMA<->VALU interleave in r1: egcl 173->188us).
//
// e_buf row layout: row' = c*64 + nl (channel-major) -> every 16-row MFMA chunk
// is channel-pure; wave w owns chunks {w, w+4, w+8} = rows its epilogue-1 wrote
// -> GEMM1->2->3 need NO barriers.
// GEMM2/GEMM3 in two ct-halves (acc[3][4] = 48 AGPR live). launch_bounds stays
// (256,2): budget floor only.
//
// Helper kernels (r6): prep-Q and finalize serial FP chains broken with
// explicit 4-way partial sums; accumulator zeroing folded into prep.

typedef short short8 __attribute__((ext_vector_type(8)));
typedef float f32x4  __attribute__((ext_vector_type(4)));
typedef unsigned int u32x2 __attribute__((ext_vector_type(2)));
typedef unsigned int u32x4 __attribute__((ext_vector_type(4)));

#define MFMA_16x16x32(a,b,c) __builtin_amdgcn_mfma_f32_16x16x32_bf16((a),(b),(c),0,0,0)

__device__ __forceinline__ float bf2f(unsigned short u) {
    return __uint_as_float(((unsigned int)u) << 16);
}
// round-half-up: 2 VALU ops; ties measure-zero for arithmetic-derived floats.
__device__ __forceinline__ unsigned short f2bf(float f) {
    return (unsigned short)((__float_as_uint(f) + 0x8000u) >> 16);
}
// Pack two f32 -> bf16x2 (round-half-up, same as f2bf), compiler-visible:
// 2x v_add_u32 + 1x v_perm_b32.
__device__ __forceinline__ unsigned int pack2bf(float lo, float hi) {
    unsigned int a = __float_as_uint(lo) + 0x8000u;
    unsigned int b = __float_as_uint(hi) + 0x8000u;
    return __builtin_amdgcn_perm(b, a, 0x07060302u);
}
__device__ __forceinline__ short8 as_short8(u32x4 v) {
    union { u32x4 u; short8 s; } x; x.u = v; return x.s;
}
__device__ __forceinline__ float silu_f(float x) {
    return x * __builtin_amdgcn_rcpf(1.0f + __expf(-x));
}

// ---------------------------------------------------------------------------
// prep: blocks [0,192) repack We1[0:128]/We2/Wc1 into bf16 MFMA B-frag order.
//   fragment k-row index kf = ks*32+(l>>4)*8+j; source row:
//     w1r  : kf          (GEMM1 contracts over raw node_feat order)
//     w2r/wc1r: g(kf) = ((kf&7)<<4)|(kf>>3)   (match pi-permuted e_buf cols)
// blocks [192,492) compute Q[b,c,h] = sum_k vnf[b,k,c]*We1[128+k,h]
// blocks [492,646) zero the accumulators (replaces hipMemsetAsync dispatch)
// ---------------------------------------------------------------------------
__global__ void prep_kernel(const float* __restrict__ We1,
                            const float* __restrict__ We2,
                            const float* __restrict__ Wc1,
                            const float* __restrict__ be1,
                            const float* __restrict__ be2,
                            const float* __restrict__ bc1,
                            const float* __restrict__ Wc2,
                            const float* __restrict__ vnf,
                            unsigned short* __restrict__ w1r,
                            unsigned short* __restrict__ w2r,
                            unsigned short* __restrict__ wc1r,
                            float* __restrict__ Q,
                            float* __restrict__ wlast,
                            float* __restrict__ be1f,
                            float* __restrict__ be2f,
                            float* __restrict__ bc1f,
                            float* __restrict__ wc2f,
                            float* __restrict__ zacc) {
    int bid = blockIdx.x;
    if (bid < 192) {
        int t = bid * 256 + threadIdx.x;   // < 49152 = 3*16384
        int m  = t / 16384;
        int e  = t % 16384;
        int j  = e & 7;
        int l  = (e >> 3) & 63;
        int ks = (e >> 9) & 3;
        int ct = e >> 11;
        int kf  = ks * 32 + (l >> 4) * 8 + j;
        int col = ct * 16 + (l & 15);
        int srck = (m == 0) ? kf : (((kf & 7) << 4) | (kf >> 3));
        const float*    src = (m == 0) ? We1 : ((m == 1) ? We2 : Wc1);
        unsigned short* dst = (m == 0) ? w1r : ((m == 1) ? w2r : wc1r);
        dst[e] = f2bf(src[srck * 128 + col]);
        if (t < 128) {
            wlast[t] = We1[256 * 128 + t];
            be1f[t]  = be1[t];
            be2f[t]  = be2[t];
            bc1f[t]  = bc1[t];
            wc2f[t]  = Wc2[t];
        }
    } else if (bid < 492) {
        int bc = bid - 192;                // 0..299
        int b = bc / NCH, c = bc % NCH;
        int t = threadIdx.x;
        __shared__ float v[128];
        if (t < 128) v[t] = vnf[(b * 128 + t) * 3 + c];
        __syncthreads();
        if (t < 128) {
            // 4 independent partials: breaks the 128-deep dependent FMA chain
            float s0 = 0.f, s1 = 0.f, s2 = 0.f, s3 = 0.f;
            for (int k = 0; k < 128; k += 4) {
                s0 += v[k + 0] * We1[(128 + k + 0) * 128 + t];
                s1 += v[k + 1] * We1[(128 + k + 1) * 128 + t];
                s2 += v[k + 2] * We1[(128 + k + 2) * 128 + t];
                s3 += v[k + 3] * We1[(128 + k + 3) * 128 + t];
            }
            Q[(b * 3 + c) * 128 + t] = (s0 + s1) + (s2 + s3);
        }
    } else {
        int idx = (bid - 492) * 256 + threadIdx.x;
        if (idx < 39400) zacc[idx] = 0.0f;   // aggsum+transsum+cnt = 157600 B
    }
}

// ---------------------------------------------------------------------------
// Main fused kernel: 64 nodes/block, 256 threads (4 waves), 3125 blocks.
// (r2 kernel, verbatim.)
// ---------------------------------------------------------------------------
__global__ __launch_bounds__(256, 2) void egcl_main(
    const float* __restrict__ node_feat,   // [N,128]
    const float* __restrict__ coord,       // [N,3]
    const float* __restrict__ vcoord,      // [B,3,C]
    const int*   __restrict__ batch,       // [N] sorted
    const unsigned short* __restrict__ w1r,
    const unsigned short* __restrict__ w2r,
    const unsigned short* __restrict__ wc1r,
    const float* __restrict__ Q,           // [B,C,H]
    const float* __restrict__ wlast,
    const float* __restrict__ be1f,
    const float* __restrict__ be2f,
    const float* __restrict__ bc1f,
    const float* __restrict__ wc2f,
    float* __restrict__ aggsum,            // [B,C,H]
    float* __restrict__ transsum,          // [B,3,C]
    float* __restrict__ cnt)               // [B]
{
    __shared__ __align__(16) unsigned short e_buf[EROWS * ESTR]; // 52224 B
    __shared__ unsigned short sbatch[BN];
    __shared__ unsigned short sseg_start[BN + 1];
    __shared__ unsigned short sseg_b[BN];
    __shared__ int snseg;

    const int tid   = threadIdx.x;
    const int wave  = tid >> 6;
    const int lane  = tid & 63;
    const int lrow  = lane & 15;           // MFMA row (A) / col (D) index
    const int lkb   = (lane >> 4) * 8;     // k-offset base within 32-wide K step
    const int rq    = (lane >> 4) * 4;     // D row-group base
    const int node0 = blockIdx.x * BN;

    // ---- Phase 0 ----
    if (tid < BN) {  // wave 0
        int n = node0 + tid;
        int b = batch[n];
        sbatch[tid] = (unsigned short)b;
        int prev = (tid > 0) ? batch[n - 1] : -1;
        unsigned long long mask = __ballot(b != prev);
        int ns = __popcll(mask);
        if (b != prev) {
            int idx = __popcll(mask & ((1ull << tid) - 1ull));
            sseg_start[idx] = (unsigned short)tid;
            sseg_b[idx]     = (unsigned short)b;
        }
        if (tid == 0) { sseg_start[ns] = BN; snseg = ns; }
        float cx = coord[n * 3 + 0];
        float cy = coord[n * 3 + 1];
        float cz = coord[n * 3 + 2];
        for (int c = 0; c < 3; ++c) {
            float dx = vcoord[b * 9 + 0 * 3 + c] - cx;
            float dy = vcoord[b * 9 + 1 * 3 + c] - cy;
            float dz = vcoord[b * 9 + 2 * 3 + c] - cz;
            f32x4 pad;
            pad[0] = dx; pad[1] = dy; pad[2] = dz;
            pad[3] = sqrtf(dx * dx + dy * dy + dz * dz);
            *(f32x4*)&e_buf[(c * 64 + tid) * ESTR + 128] = pad;  // 16B aligned
        }
    }
    __syncthreads();
    const int nseg = snseg;   // block-uniform

    // ---- GEMM1: P[64,128] = node_feat_tile @ We1_top; wave w -> nodes 16w..16w+15
    f32x4 acc1[8] = {};
    {
        const float* arow = node_feat + (size_t)(node0 + wave * 16 + lrow) * 128;
        for (int ks = 0; ks < 4; ++ks) {
            f32x4 x0 = *(const f32x4*)(arow + ks * 32 + lkb);
            f32x4 x1 = *(const f32x4*)(arow + ks * 32 + lkb + 4);
            u32x4 av;
            av[0] = pack2bf(x0[0], x0[1]);
            av[1] = pack2bf(x0[2], x0[3]);
            av[2] = pack2bf(x1[0], x1[1]);
            av[3] = pack2bf(x1[2], x1[3]);
            short8 af = as_short8(av);
            for (int ct = 0; ct < 8; ++ct) {
                short8 bfg = *(const short8*)(w1r + ((ct * 4 + ks) * 64 + lane) * 8);
                acc1[ct] = MFMA_16x16x32(af, bfg, acc1[ct]);
            }
        }
    }
    // Epilogue 1: E1[row, pi(h)] = bf16(silu(P + Q[b,c,h] + radial*wlast[h] + be1[h]))
    // Lane's 8 values (h = ct*16+lrow, ct=0..7) land at cols lrow*8..lrow*8+7
    // -> one ds_write_b128 per (r,c). Per-quarter: 16 lanes, same row,
    // contiguous 256B.
    {
        float wl[8];
        #pragma unroll
        for (int ct = 0; ct < 8; ++ct)
            wl[ct] = wlast[ct * 16 + lrow];
        if (nseg == 1) {
            const float* qb = Q + (int)sseg_b[0] * (NCH * HD);
            float qv[3][8];   // bias folded in
            #pragma unroll
            for (int c = 0; c < 3; ++c)
                #pragma unroll
                for (int ct = 0; ct < 8; ++ct)
                    qv[c][ct] = qb[c * 128 + ct * 16 + lrow] + be1f[ct * 16 + lrow];
            #pragma unroll
            for (int r = 0; r < 4; ++r) {
                int nl = wave * 16 + rq + r;
                #pragma unroll
                for (int c = 0; c < 3; ++c) {
                    int row = c * 64 + nl;
                    float rad = *(const float*)&e_buf[row * ESTR + 134];
                    float v[8];
                    #pragma unroll
                    for (int ct = 0; ct < 8; ++ct)
                        v[ct] = silu_f(acc1[ct][r] + qv[c][ct] + rad * wl[ct]);
                    u32x4 av;
                    av[0] = pack2bf(v[0], v[1]);
                    av[1] = pack2bf(v[2], v[3]);
                    av[2] = pack2bf(v[4], v[5]);
                    av[3] = pack2bf(v[6], v[7]);
                    *(u32x4*)&e_buf[row * ESTR + lrow * 8] = av;
                }
            }
        } else {
            float bb[8];
            #pragma unroll
            for (int ct = 0; ct < 8; ++ct)
                bb[ct] = be1f[ct * 16 + lrow];
            #pragma unroll
            for (int r = 0; r < 4; ++r) {
                int nl = wave * 16 + rq + r;
                int b  = sbatch[nl];
                #pragma unroll
                for (int c = 0; c < 3; ++c) {
                    int row = c * 64 + nl;
                    float rad = *(const float*)&e_buf[row * ESTR + 134];
                    const float* qb = Q + (b * 3 + c) * 128;
                    float v[8];
                    #pragma unroll
                    for (int ct = 0; ct < 8; ++ct)
                        v[ct] = silu_f(acc1[ct][r] + bb[ct] + qb[ct * 16 + lrow]
                                       + rad * wl[ct]);
                    u32x4 av;
                    av[0] = pack2bf(v[0], v[1]);
                    av[1] = pack2bf(v[2], v[3]);
                    av[2] = pack2bf(v[4], v[5]);
                    av[3] = pack2bf(v[6], v[7]);
                    *(u32x4*)&e_buf[row * ESTR + lrow * 8] = av;
                }
            }
        }
    }
    // (no barrier: wave w's chunks {w, w+4, w+8} are exactly the rows it wrote;
    //  radial in pad col 134 is now dead for this wave's rows)

    const int bagg = (nseg == 1) ? (int)sseg_b[0] * (NCH * HD) : 0;

    // ---- GEMM2: M = silu(E1 @ We2 + be2), in two ct-halves (48 AGPR live) ----
    // A-fragment cols are pi-permuted; w2r rows were repacked through g() so
    // the contraction matches.
    for (int half = 0; half < 2; ++half) {
        f32x4 acc[3][4] = {};
        for (int ks = 0; ks < 4; ++ks) {
            short8 af[3];
            #pragma unroll
            for (int j = 0; j < 3; ++j)
                af[j] = *(const short8*)(&e_buf[(j * 64 + wave * 16 + lrow) * ESTR +
                                                ks * 32 + lkb]);
            #pragma unroll
            for (int c4 = 0; c4 < 4; ++c4) {
                int ct = half * 4 + c4;
                short8 bfg = *(const short8*)(w2r + ((ct * 4 + ks) * 64 + lane) * 8);
                #pragma unroll
                for (int j = 0; j < 3; ++j)
                    acc[j][c4] = MFMA_16x16x32(af[j], bfg, acc[j][c4]);
            }
        }
        // Epilogue 2 (this half): lane's 4 values -> cols lrow*8+half*4.. (+4)
        // -> one ds_write_b64 per (j,r). Plus fast-path segment-sum.
        float b0 = be2f[(half * 4 + 0) * 16 + lrow];
        float b1 = be2f[(half * 4 + 1) * 16 + lrow];
        float b2 = be2f[(half * 4 + 2) * 16 + lrow];
        float b3 = be2f[(half * 4 + 3) * 16 + lrow];
        #pragma unroll
        for (int j = 0; j < 3; ++j) {
            float ps0 = 0.f, ps1 = 0.f, ps2 = 0.f, ps3 = 0.f;
            #pragma unroll
            for (int r = 0; r < 4; ++r) {
                int row = j * 64 + wave * 16 + rq + r;
                float v0 = silu_f(acc[j][0][r] + b0);
                float v1 = silu_f(acc[j][1][r] + b1);
                float v2 = silu_f(acc[j][2][r] + b2);
                float v3 = silu_f(acc[j][3][r] + b3);
                ps0 += v0; ps1 += v1; ps2 += v2; ps3 += v3;
                u32x2 dv;
                dv[0] = pack2bf(v0, v1);
                dv[1] = pack2bf(v2, v3);
                *(u32x2*)&e_buf[row * ESTR + lrow * 8 + half * 4] = dv;
            }
            if (nseg == 1) {
                ps0 += __shfl_xor(ps0, 16, 64); ps0 += __shfl_xor(ps0, 32, 64);
                ps1 += __shfl_xor(ps1, 16, 64); ps1 += __shfl_xor(ps1, 32, 64);
                ps2 += __shfl_xor(ps2, 16, 64); ps2 += __shfl_xor(ps2, 32, 64);
                ps3 += __shfl_xor(ps3, 16, 64); ps3 += __shfl_xor(ps3, 32, 64);
                if (lane < 16) {
                    atomicAdd(&aggsum[bagg + j * 128 + (half * 4 + 0) * 16 + lane], ps0);
                    atomicAdd(&aggsum[bagg + j * 128 + (half * 4 + 1) * 16 + lane], ps1);
                    atomicAdd(&aggsum[bagg + j * 128 + (half * 4 + 2) * 16 + lane], ps2);
                    atomicAdd(&aggsum[bagg + j * 128 + (half * 4 + 3) * 16 + lane], ps3);
                }
            }
        }
    }

    // ---- GEMM3: SH = silu(M @ Wc1 + bc1); s = SH . Wc2, two ct-halves ----
    float p[3][4] = {};
    for (int half = 0; half < 2; ++half) {
        f32x4 acc[3][4] = {};
        for (int ks = 0; ks < 4; ++ks) {
            short8 af[3];
            #pragma unroll
            for (int j = 0; j < 3; ++j)
                af[j] = *(const short8*)(&e_buf[(j * 64 + wave * 16 + lrow) * ESTR +
                                                ks * 32 + lkb]);
            #pragma unroll
            for (int c4 = 0; c4 < 4; ++c4) {
                int ct = half * 4 + c4;
                short8 bfg = *(const short8*)(wc1r + ((ct * 4 + ks) * 64 + lane) * 8);
                #pragma unroll
                for (int j = 0; j < 3; ++j)
                    acc[j][c4] = MFMA_16x16x32(af[j], bfg, acc[j][c4]);
            }
        }
        float b0 = bc1f[(half * 4 + 0) * 16 + lrow];
        float b1 = bc1f[(half * 4 + 1) * 16 + lrow];
        float b2 = bc1f[(half * 4 + 2) * 16 + lrow];
        float b3 = bc1f[(half * 4 + 3) * 16 + lrow];
        float w0 = wc2f[(half * 4 + 0) * 16 + lrow];
        float w1 = wc2f[(half * 4 + 1) * 16 + lrow];
        float w2 = wc2f[(half * 4 + 2) * 16 + lrow];
        float w3 = wc2f[(half * 4 + 3) * 16 + lrow];
        #pragma unroll
        for (int j = 0; j < 3; ++j) {
            #pragma unroll
            for (int r = 0; r < 4; ++r) {
                float s = p[j][r];
                s += silu_f(acc[j][0][r] + b0) * w0;
                s += silu_f(acc[j][1][r] + b1) * w1;
                s += silu_f(acc[j][2][r] + b2) * w2;
                s += silu_f(acc[j][3][r] + b3) * w3;
                p[j][r] = s;
            }
        }
    }
    for (int j = 0; j < 3; ++j) {
        float p0 = p[j][0], p1 = p[j][1], p2 = p[j][2], p3 = p[j][3];
        #pragma unroll
        for (int off = 1; off < 16; off <<= 1) {
            p0 += __shfl_xor(p0, off, 64);
            p1 += __shfl_xor(p1, off, 64);
            p2 += __shfl_xor(p2, off, 64);
            p3 += __shfl_xor(p3, off, 64);
        }
        if (lrow == 0) {   // s -> pad col 134 (old radial slot), wave-private rows
            int rbase = j * 64 + wave * 16 + rq;
            *(float*)&e_buf[(rbase + 0) * ESTR + 134] = p0;
            *(float*)&e_buf[(rbase + 1) * ESTR + 134] = p1;
            *(float*)&e_buf[(rbase + 2) * ESTR + 134] = p2;
            *(float*)&e_buf[(rbase + 3) * ESTR + 134] = p3;
        }
    }
    __syncthreads();

    // ---- Reduce to global (aggsum fast path already done in epilogue 2) ----
    if (nseg == 1) {
        int b = sseg_b[0];
        if (wave == 0) {   // trans: 64-lane shuffle tree over nodes
            float t[9];
            #pragma unroll
            for (int c = 0; c < 3; ++c) {
                int row = c * 64 + lane;
                float sv = *(const float*)&e_buf[row * ESTR + 134];
                float dx = *(const float*)&e_buf[row * ESTR + 128];
                float dy = *(const float*)&e_buf[row * ESTR + 130];
                float dz = *(const float*)&e_buf[row * ESTR + 132];
                t[0 * 3 + c] = dx * sv;
                t[1 * 3 + c] = dy * sv;
                t[2 * 3 + c] = dz * sv;
            }
            #pragma unroll
            for (int off = 1; off < 64; off <<= 1)
                #pragma unroll
                for (int k = 0; k < 9; ++k)
                    t[k] += __shfl_xor(t[k], off, 64);
            if (lane < 9)
                atomicAdd(&transsum[b * 9 + lane],
                          __shfl(t[lane], 0, 64));  // lane0 holds full sums
            if (lane == 0) atomicAdd(&cnt[b], 64.0f);
        }
    } else {
        for (int sg = 0; sg < nseg; ++sg) {
            int s0 = sseg_start[sg], s1 = sseg_start[sg + 1], b = sseg_b[sg];
            for (int idx = tid; idx < NCH * HD; idx += 256) {
                int c = idx >> 7, pcol = idx & 127;
                float sum = 0.f;
                for (int ii = s0; ii < s1; ++ii)
                    sum += bf2f(e_buf[(c * 64 + ii) * ESTR + pcol]);
                int h = ((pcol & 7) << 4) | (pcol >> 3);   // g(p): undo pi
                atomicAdd(&aggsum[(b * 3 + c) * 128 + h], sum);
            }
            if (tid < 9) {
                int d = tid / 3, c = tid % 3;
                float sum = 0.f;
                for (int ii = s0; ii < s1; ++ii)
                    sum += (*(const float*)&e_buf[(c * 64 + ii) * ESTR + 128 + 2 * d])
                           * (*(const float*)&e_buf[(c * 64 + ii) * ESTR + 134]);
                atomicAdd(&transsum[b * 9 + d * 3 + c], sum);
            }
            if (tid == 0) atomicAdd(&cnt[b], (float)(s1 - s0));
        }
    }
}

// ---------------------------------------------------------------------------
// Finalize: one block per (b,c) row. Means, node model, residuals, outputs.
// Serial FP chains broken with explicit partial sums (r6).
// ---------------------------------------------------------------------------
__global__ void finalize_kernel(const float* __restrict__ vnf,
                                const float* __restrict__ vcoord,
                                const float* __restrict__ Wn1,
                                const float* __restrict__ bn1,
                                const float* __restrict__ Wn2,
                                const float* __restrict__ bn2,
                                const float* __restrict__ aggsum,
                                const float* __restrict__ transsum,
                                const float* __restrict__ cnt,
                                float* __restrict__ out) {
    int b = blockIdx.x / NCH;
    int c = blockIdx.x % NCH;
    int j = threadIdx.x;   // 0..127
    __shared__ float nin[256];
    __shared__ float h1[128];
    float count = fmaxf(cnt[b], 1.0f);
    nin[j]       = vnf[(b * 128 + j) * 3 + c];
    nin[128 + j] = aggsum[(b * 3 + c) * 128 + j] / count;
    __syncthreads();
    float x0 = bn1[j], x1 = 0.f, x2 = 0.f, x3 = 0.f;
    for (int k = 0; k < 256; k += 4) {
        x0 += nin[k + 0] * Wn1[(k + 0) * 128 + j];
        x1 += nin[k + 1] * Wn1[(k + 1) * 128 + j];
        x2 += nin[k + 2] * Wn1[(k + 2) * 128 + j];
        x3 += nin[k + 3] * Wn1[(k + 3) * 128 + j];
    }
    h1[j] = silu_f((x0 + x1) + (x2 + x3));
    __syncthreads();
    float y0 = bn2[j], y1 = 0.f, y2 = 0.f, y3 = 0.f;
    for (int k = 0; k < 128; k += 4) {
        y0 += h1[k + 0] * Wn2[(k + 0) * 128 + j];
        y1 += h1[k + 1] * Wn2[(k + 1) * 128 + j];
        y2 += h1[k + 2] * Wn2[(k + 2) * 128 + j];
        y3 += h1[k + 3] * Wn2[(k + 3) * 128 + j];
    }
    float y = (y0 + y1) + (y2 + y3);
    out[(b * 128 + j) * 3 + c] = vnf[(b * 128 + j) * 3 + c] + y;
    if (c == 0 && j < 9) {
        out[NGRAPH * 128 * 3 + b * 9 + j] =
            vcoord[b * 9 + j] + transsum[b * 9 + j] / count;
    }
}

// ---------------------------------------------------------------------------
extern "C" void kernel_launch(void* const* d_in, const int* in_sizes, int n_in,
                              void* d_out, int out_size, void* d_ws, size_t ws_size,
                              hipStream_t stream) {
    const float* node_feat = (const float*)d_in[0];
    const float* coord     = (const float*)d_in[1];
    const float* vnf       = (const float*)d_in[2];
    const float* vcoord    = (const float*)d_in[3];
    const int*   batch     = (const int*)d_in[4];
    const float* We1 = (const float*)d_in[5];
    const float* be1 = (const float*)d_in[6];
    const float* We2 = (const float*)d_in[7];
    const float* be2 = (const float*)d_in[8];
    const float* Wc1 = (const float*)d_in[9];
    const float* bc1 = (const float*)d_in[10];
    const float* Wc2 = (const float*)d_in[11];
    const float* Wn1 = (const float*)d_in[12];
    const float* bn1 = (const float*)d_in[13];
    const float* Wn2 = (const float*)d_in[14];
    const float* bn2 = (const float*)d_in[15];

    char* ws = (char*)d_ws;
    float*          aggsum   = (float*)(ws + 0);          // 153600
    float*          transsum = (float*)(ws + 153600);     // 3600
    float*          cntp     = (float*)(ws + 157200);     // 400
    float*          Q        = (float*)(ws + 157600);     // 153600
    unsigned short* w1r      = (unsigned short*)(ws + 311200); // 32768
    unsigned short* w2r      = (unsigned short*)(ws + 343968); // 32768
    unsigned short* wc1r     = (unsigned short*)(ws + 376736); // 32768
    float*          wlast    = (float*)(ws + 409504);
    float*          be1f     = (float*)(ws + 410016);
    float*          be2f     = (float*)(ws + 410528);
    float*          bc1f     = (float*)(ws + 411040);
    float*          wc2f     = (float*)(ws + 411552);

    // accumulator zeroing folded into prep_kernel (blocks [492,646)).
    prep_kernel<<<192 + NGRAPH * NCH + 154, 256, 0, stream>>>(
        We1, We2, Wc1, be1, be2, bc1, Wc2, vnf,
        w1r, w2r, wc1r, Q, wlast, be1f, be2f, bc1f, wc2f,
        (float*)ws);

    egcl_main<<<NNODES / BN, 256, 0, stream>>>(
        node_feat, coord, vcoord, batch, w1r, w2r, wc1r, Q,
        wlast, be1f, be2f, bc1f, wc2f, aggsum, transsum, cntp);

    finalize_kernel<<<NGRAPH * NCH, 128, 0, stream>>>(
        vnf, vcoord, Wn1, bn1, Wn2, bn2, aggsum, transsum, cntp,
        (float*)d_out);
}